// Round 1
// baseline (258.069 us; speedup 1.0000x reference)
//
#include <hip/hip_runtime.h>

// pos[b][f][i][j] = row_embed[Z(i,j)][f],  Z = max(|32-j| + |32-i| - 1, 0)
// b=32, F=512, h=w=64. Output fp32, 256 MiB -> pure write-BW bound.
//
// R1 lesson: 32-way batch fan-out per wave (stores 8 MiB apart) broke the
//   linear write stream -> ~1 TB/s vs memset's 6.6 TB/s.
// R2 lesson: one block per (b,f), contiguous 16 KB per block -> kernel ~92 us
//   (2.9 TB/s), still 2.2x off the 6.55 TB/s the harness's own fill achieves.
//   16384 short-lived blocks = gather-prologue + barrier + only 4 store insts
//   per wave; wave-lifetime is not memset-shaped.
// R3 structure: the image depends only on f, never on b. Grid = 2048 blocks
//   (exactly 8 blocks/CU on 256 CUs, full static occupancy, no block
//   re-sequencing). Block g stages col[] once, computes its 16 values once
//   into registers, then writes the SAME image to 8 batch copies
//   bf = g + 2048*t  (f = g & 511 is invariant; b = (g>>9) + 4t).
//   Each image-pass t: blocks jointly cover a dense 32 MiB window with
//   consecutive-block -> consecutive-16KB chunks (R2's stream property kept),
//   and each wave now issues 32 independent contiguous 1 KB stores.

#define NUM_POS_FEATS 512
#define H 64
#define W 64
#define B 32
#define GRID 2048
#define IMGS_PER_BLOCK ((B * NUM_POS_FEATS) / GRID)   // 8

__global__ __launch_bounds__(256) void pe_kernel(const float* __restrict__ row_embed,
                                                 float* __restrict__ out) {
    __shared__ float col[64];   // row_embed[z][f] for z in [0,64)

    const int g   = blockIdx.x;                 // 0..2047
    const int f   = g & (NUM_POS_FEATS - 1);    // invariant across this block's images
    const int tid = threadIdx.x;

    if (tid < 64) {
        col[tid] = row_embed[tid * NUM_POS_FEATS + f];
    }
    __syncthreads();

    // Compute this thread's 16 output values ONCE (image is independent of b).
    float4 v[4];
#pragma unroll
    for (int k = 0; k < 4; ++k) {
        const int idx = k * 256 + tid;          // quad index 0..1023 within image
        const int i   = idx >> 4;               // row
        const int j4  = (idx & 15) << 2;        // quad start column
        const int di  = abs(32 - i);

        int z0 = di + abs(32 - (j4 + 0)) - 1; v[k].x = col[z0 < 0 ? 0 : z0];
        int z1 = di + abs(32 - (j4 + 1)) - 1; v[k].y = col[z1 < 0 ? 0 : z1];
        int z2 = di + abs(32 - (j4 + 2)) - 1; v[k].z = col[z2 < 0 ? 0 : z2];
        int z3 = di + abs(32 - (j4 + 3)) - 1; v[k].w = col[z3 < 0 ? 0 : z3];
    }

    // 8 images, 32 MiB apart: bf = g + GRID*t  ->  quad offset g*1024 + t*GRID*1024.
    float4*      o    = reinterpret_cast<float4*>(out) + (size_t)g * (H * W / 4);
    const size_t step = (size_t)GRID * (H * W / 4);     // 2048 * 1024 quads = 32 MiB

#pragma unroll
    for (int t = 0; t < IMGS_PER_BLOCK; ++t) {
#pragma unroll
        for (int k = 0; k < 4; ++k) {
            o[k * 256 + tid] = v[k];            // contiguous 1 KB per wave per store
        }
        o += step;
    }
}

extern "C" void kernel_launch(void* const* d_in, const int* in_sizes, int n_in,
                              void* d_out, int out_size, void* d_ws, size_t ws_size,
                              hipStream_t stream) {
    // d_in[0] = x (32,3,64,64) fp32 — unused (shape only)
    // d_in[1] = row_embed (64,512) fp32
    const float* row_embed = (const float*)d_in[1];
    float* out = (float*)d_out;

    pe_kernel<<<GRID, 256, 0, stream>>>(row_embed, out);
}